// Round 6
// baseline (30052.081 us; speedup 1.0000x reference)
//
#include <hip/hip_runtime.h>
#include <math.h>
#include <stdint.h>

#define BB 2048
#define TT 100
#define DD 128
#define HH 256
#define NEGF -1.0e9f

#define NBLK 256          // decoder blocks
#define ROWS 8            // valid batch rows per block (decoder)
#define RA   16           // A-tile rows (MFMA M), rows 8..15 stay zero in decoder
#define NTHR 1024         // 16 waves
#define KTOT 384          // 128 (x) + 256 (h)
#define NKF  12           // K fragments (K=32 each)
#define ASTR 392          // shorts per A-LDS row (384 + 8 pad)

typedef __attribute__((ext_vector_type(8))) short short8_t;   // 8 bf16
typedef __attribute__((ext_vector_type(4))) float f32x4;

#define MFMA16(a,b,c) __builtin_amdgcn_mfma_f32_16x16x32_bf16((a),(b),(c),0,0,0)
// 6-product bf16x6 accumulate, small terms first (exact-split fp32 emulation)
#define MFMA_X6(aH,aM,aL,bH,bM,bL,acc)            \
  do{ acc = MFMA16(aM, bM, acc);                  \
      acc = MFMA16(aH, bL, acc);                  \
      acc = MFMA16(aL, bH, acc);                  \
      acc = MFMA16(aH, bM, acc);                  \
      acc = MFMA16(aM, bH, acc);                  \
      acc = MFMA16(aH, bH, acc); }while(0)

__device__ __forceinline__ float sigmoidf_(float x){ return 1.0f/(1.0f+expf(-x)); }

// fast tanh for scores only: HW exp + HW rcp. |rel err| ~1e-7.
__device__ __forceinline__ float tanh_fast(float x){
  x = fminf(15.f, fmaxf(-15.f, x));
  const float e = __expf(x + x);
  return (e - 1.f) * __builtin_amdgcn_rcpf(e + 1.f);
}

// 3-way bf16 split: x == h + m + l EXACTLY (24 mantissa bits covered).
__device__ __forceinline__ void bf16_split3(float x, unsigned short &h,
                                            unsigned short &m, unsigned short &l){
  const unsigned u = __float_as_uint(x);
  const unsigned r = u + 0x7FFFu + ((u >> 16) & 1u);
  h = (unsigned short)(r >> 16);
  const float rem = x - __uint_as_float(r & 0xFFFF0000u);
  const unsigned u2 = __float_as_uint(rem);
  const unsigned r2 = u2 + 0x7FFFu + ((u2 >> 16) & 1u);
  m = (unsigned short)(r2 >> 16);
  const float rem2 = rem - __uint_as_float(r2 & 0xFFFF0000u);
  l = (unsigned short)(__float_as_uint(rem2) >> 16);
}

__global__ __launch_bounds__(256) void k_split3(const float* __restrict__ src,
    unsigned short* __restrict__ hi, unsigned short* __restrict__ mi,
    unsigned short* __restrict__ lo, int n){
  const int i = blockIdx.x*256 + threadIdx.x;
  if(i < n){ unsigned short h,m,l; bf16_split3(src[i], h, m, l);
             hi[i]=h; mi[i]=m; lo[i]=l; }
}

// Pack {w_ih[1024][128], w_hh[1024][256]} -> fragment-ordered bf16x3:
// element i = ((f*NKF + kf)*64 + lane)*8 + e  <->  n = f*16+(lane&15),
// k = kf*32 + (lane>>4)*8 + e.  B-frag load = one coalesced 16B/lane read.
__global__ __launch_bounds__(256) void k_packW(
    const float* __restrict__ w_ih, const float* __restrict__ w_hh,
    unsigned short* __restrict__ WfH, unsigned short* __restrict__ WfM,
    unsigned short* __restrict__ WfL)
{
  const int i = blockIdx.x*256 + threadIdx.x;
  if(i >= 1024*KTOT) return;
  const int f    = i / (NKF*64*8);
  const int r1   = i % (NKF*64*8);
  const int kf   = r1 >> 9;
  const int r2   = r1 & 511;
  const int lane = r2 >> 3;
  const int e    = r2 & 7;
  const int n = f*16 + (lane & 15);
  const int k = kf*32 + (lane >> 4)*8 + e;
  const float w = (k < DD) ? w_ih[(size_t)n*DD + k] : w_hh[(size_t)n*HH + (k-DD)];
  unsigned short h,m,l; bf16_split3(w,h,m,l);
  WfH[i]=h; WfM[i]=m; WfL[i]=l;
}

// Pack W2[256][256] -> fragments: f2 in 0..15, kf2 in 0..7.
__global__ __launch_bounds__(256) void k_packW2(
    const float* __restrict__ W2,
    unsigned short* __restrict__ WfH, unsigned short* __restrict__ WfM,
    unsigned short* __restrict__ WfL)
{
  const int i = blockIdx.x*256 + threadIdx.x;
  if(i >= 256*256) return;
  const int f2   = i >> 12;          // / 4096
  const int r1   = i & 4095;
  const int kf2  = r1 >> 9;
  const int r2   = r1 & 511;
  const int lane = r2 >> 3;
  const int e    = r2 & 7;
  const int n = f2*16 + (lane & 15);
  const int k = kf2*32 + (lane >> 4)*8 + e;
  unsigned short h,m,l; bf16_split3(W2[(size_t)n*HH + k], h, m, l);
  WfH[i]=h; WfM[i]=m; WfL[i]=l;
}

// swizzled A-LDS short-index: row stride ASTR shorts, XOR bit4 of byte offset by row&7
__device__ __forceinline__ int swA(int row, int byteoff){
  return row*ASTR + (((byteoff) ^ ((row & 7) << 4)) >> 1);
}

// ============ encoder: 128 blocks x 16 rows, 100 steps in-block, 16 waves ====
__global__ __launch_bounds__(NTHR) void k_encoder(
    const float* __restrict__ targets,
    const unsigned short* __restrict__ WfH, const unsigned short* __restrict__ WfM,
    const unsigned short* __restrict__ WfL,
    const float* __restrict__ bih, const float* __restrict__ bhh,
    float* __restrict__ blend1)
{
  __shared__ unsigned short AsH[RA*ASTR], AsM[RA*ASTR], AsL[RA*ASTR];
  const int tid = threadIdx.x;
  const int lane = tid & 63;
  const int wv = tid >> 6;                   // 0..15
  const int l15 = lane & 15, l4 = lane >> 4;
  const int b0 = blockIdx.x * RA;            // 16 rows per encoder block

  const int j = wv*16 + l15;                 // output H-col of this lane
  float bias[4];
  #pragma unroll
  for(int g=0; g<4; g++) bias[g] = bih[g*HH + j] + bhh[g*HH + j];

  float cst[4];
  #pragma unroll
  for(int r=0;r<4;r++) cst[r] = 0.f;

  for(int i=tid; i<RA*ASTR; i+=NTHR){ AsH[i]=0; AsM[i]=0; AsL[i]=0; }

  const int srow = tid >> 6;                 // x staging: row 0..15
  const int k2   = (tid & 63) * 2;           // 2 k-elems per thread

  for(int t=0; t<TT; t++){
    __syncthreads();                         // prev gates reads + epilogue done
    {                                        // stage x = targets[:, t, :] split3
      const float2 v = *(const float2*)(targets + ((size_t)(b0+srow)*TT + t)*DD + k2);
      unsigned short h0,m0_,l0,h1,m1_,l1;
      bf16_split3(v.x,h0,m0_,l0); bf16_split3(v.y,h1,m1_,l1);
      const int idx = swA(srow, k2*2);
      *(ushort2*)&AsH[idx] = make_ushort2(h0,h1);
      *(ushort2*)&AsM[idx] = make_ushort2(m0_,m1_);
      *(ushort2*)&AsL[idx] = make_ushort2(l0,l1);
    }
    __syncthreads();
    f32x4 acc[4];
    #pragma unroll
    for(int g=0; g<4; g++){
      acc[g][0]=bias[g]; acc[g][1]=bias[g]; acc[g][2]=bias[g]; acc[g][3]=bias[g];
    }
    for(int kf=0; kf<NKF; kf++){
      const int ao = swA(l15, kf*64 + l4*16);
      const short8_t aH = *(const short8_t*)&AsH[ao];
      const short8_t aM = *(const short8_t*)&AsM[ao];
      const short8_t aL = *(const short8_t*)&AsL[ao];
      #pragma unroll
      for(int g=0; g<4; g++){
        const int f = g*16 + wv;
        const size_t wo = ((size_t)(f*NKF + kf)*64 + lane)*8;
        const short8_t bH = *(const short8_t*)(WfH + wo);
        const short8_t bM = *(const short8_t*)(WfM + wo);
        const short8_t bL = *(const short8_t*)(WfL + wo);
        MFMA_X6(aH,aM,aL,bH,bM,bL, acc[g]);
      }
    }
    __syncthreads();                         // A-frag reads done before h writes
    #pragma unroll
    for(int r=0; r<4; r++){
      const int row = l4*4 + r;
      const float iv = acc[0][r];
      const float fv = acc[1][r];
      const float gv = acc[2][r];
      const float ov = acc[3][r];
      const float cn = sigmoidf_(fv)*cst[r] + sigmoidf_(iv)*tanhf(gv);
      const float hn = sigmoidf_(ov)*tanhf(cn);
      cst[r] = cn;
      unsigned short sh, sm_, sl;
      bf16_split3(hn, sh, sm_, sl);
      const int hi = swA(row, (128 + j)*2);
      AsH[hi] = sh; AsM[hi] = sm_; AsL[hi] = sl;
      blend1[((size_t)(b0+row)*TT + t)*256 + j] = hn;
    }
  }
}

// ============ decoder: 256 blocks x 8 rows, 16 waves, all phases in-block ====
__global__ __launch_bounds__(NTHR) void k_decoder(
    const float* __restrict__ targets,
    const unsigned short* __restrict__ WfH, const unsigned short* __restrict__ WfM,
    const unsigned short* __restrict__ WfL,
    const unsigned short* __restrict__ W2fH, const unsigned short* __restrict__ W2fM,
    const unsigned short* __restrict__ W2fL,
    const float* __restrict__ bih, const float* __restrict__ bhh,
    const float* __restrict__ h0, const float* __restrict__ c0,
    const float* __restrict__ vt,
    const float* __restrict__ blend1,
    float* __restrict__ outp)
{
  __shared__ unsigned short AsH[RA*ASTR], AsM[RA*ASTR], AsL[RA*ASTR];
  __shared__ float b2s[ROWS*264];
  __shared__ float sc[ROWS][104];
  __shared__ float vts[256];
  __shared__ char selc[ROWS][104];
  const int tid = threadIdx.x;
  const int lane = tid & 63;
  const int wv = tid >> 6;                   // 0..15
  const int l15 = lane & 15, l4 = lane >> 4;
  const int b0 = blockIdx.x * ROWS;

  const int j = wv*16 + l15;
  float bias[4];
  #pragma unroll
  for(int g=0; g<4; g++) bias[g] = bih[g*HH + j] + bhh[g*HH + j];

  for(int i=tid; i<RA*ASTR; i+=NTHR){ AsH[i]=0; AsM[i]=0; AsL[i]=0; } // x=0 @ st0, rows 8..15 stay 0
  if(tid < 256) vts[tid] = vt[tid];
  for(int i=tid; i<ROWS*104; i+=NTHR) (&selc[0][0])[i] = 0;
  {                                          // h0 -> A h-region split3 (8 rows)
    const int row = tid >> 7;                // 0..7
    const int k2  = (tid & 127) * 2;
    const float2 v = *(const float2*)(h0 + (size_t)(b0+row)*HH + k2);
    unsigned short h0_,m0_,l0,h1,m1_,l1;
    bf16_split3(v.x,h0_,m0_,l0); bf16_split3(v.y,h1,m1_,l1);
    const int idx = swA(row, (128 + k2)*2);
    *(ushort2*)&AsH[idx] = make_ushort2(h0_,h1);
    *(ushort2*)&AsM[idx] = make_ushort2(m0_,m1_);
    *(ushort2*)&AsL[idx] = make_ushort2(l0,l1);
  }
  float cst[4];
  #pragma unroll
  for(int r=0; r<4; r++)
    cst[r] = (l4 < 2) ? c0[(size_t)(b0 + l4*4 + r)*HH + j] : 0.f;

  for(int st=0; st<TT; st++){
    __syncthreads();                         // gather/epilogue writes visible
    // ---- phase A: gates GEMM (bf16x6 MFMA) ----
    f32x4 acc[4];
    #pragma unroll
    for(int g=0; g<4; g++){
      acc[g][0]=bias[g]; acc[g][1]=bias[g]; acc[g][2]=bias[g]; acc[g][3]=bias[g];
    }
    for(int kf=0; kf<NKF; kf++){
      const int ao = swA(l15, kf*64 + l4*16);
      const short8_t aH = *(const short8_t*)&AsH[ao];
      const short8_t aM = *(const short8_t*)&AsM[ao];
      const short8_t aL = *(const short8_t*)&AsL[ao];
      #pragma unroll
      for(int g=0; g<4; g++){
        const int f = g*16 + wv;
        const size_t wo = ((size_t)(f*NKF + kf)*64 + lane)*8;
        const short8_t bH = *(const short8_t*)(WfH + wo);
        const short8_t bM = *(const short8_t*)(WfM + wo);
        const short8_t bL = *(const short8_t*)(WfL + wo);
        MFMA_X6(aH,aM,aL,bH,bM,bL, acc[g]);
      }
    }
    __syncthreads();                         // A-frag reads done before h writes
    // ---- cell epilogue: rows < 8 only; h_new split3 -> A h-region ----
    if(l4 < 2){
      #pragma unroll
      for(int r=0; r<4; r++){
        const int row = l4*4 + r;
        const float iv = acc[0][r];
        const float fv = acc[1][r];
        const float gv = acc[2][r];
        const float ov = acc[3][r];
        const float cn = sigmoidf_(fv)*cst[r] + sigmoidf_(iv)*tanhf(gv);
        const float hn = sigmoidf_(ov)*tanhf(cn);
        cst[r] = cn;
        unsigned short sh, sm_, sl;
        bf16_split3(hn, sh, sm_, sl);
        const int hi = swA(row, (128 + j)*2);
        AsH[hi] = sh; AsM[hi] = sm_; AsL[hi] = sl;
      }
    }
    __syncthreads();                         // h-region ready
    // ---- blend2 = h_new @ W2^T (bf16x6 MFMA), wave wv owns n-frag f2=wv ----
    {
      f32x4 b2acc;
      b2acc[0]=0.f; b2acc[1]=0.f; b2acc[2]=0.f; b2acc[3]=0.f;
      for(int kf2=0; kf2<8; kf2++){
        const int ao = swA(l15, (kf2+4)*64 + l4*16);
        const short8_t aH = *(const short8_t*)&AsH[ao];
        const short8_t aM = *(const short8_t*)&AsM[ao];
        const short8_t aL = *(const short8_t*)&AsL[ao];
        const size_t wo = ((size_t)(wv*8 + kf2)*64 + lane)*8;
        const short8_t bH = *(const short8_t*)(W2fH + wo);
        const short8_t bM = *(const short8_t*)(W2fM + wo);
        const short8_t bL = *(const short8_t*)(W2fL + wo);
        MFMA_X6(aH,aM,aL,bH,bM,bL, b2acc);
      }
      if(l4 < 2){
        #pragma unroll
        for(int r=0; r<4; r++)
          b2s[(l4*4 + r)*264 + wv*16 + l15] = b2acc[r];
      }
    }
    __syncthreads();                         // b2s ready
    // ---- scores: 2 waves per row, 4 t per iter, 16-lane-group reduce ----
    {
      const int row = wv >> 1;
      const int tb0 = wv & 1;
      const int g4 = lane >> 4, l16 = lane & 15;
      const float* bl  = blend1 + (size_t)(b0+row)*TT*256;
      const float* b2p = &b2s[row*264];
      #pragma unroll
      for(int i=0; i<13; i++){
        const int tb = tb0 + 2*i;
        if(tb < 25){                         // tb==25 tail (t>=100) skipped
          const int t = tb*4 + g4;
          float p = 0.f;
          #pragma unroll
          for(int q=0; q<4; q++){
            const int k = q*64 + l16*4;
            const float4 x   = *(const float4*)(bl + (size_t)t*256 + k);
            const float4 bv  = *(const float4*)(b2p + k);
            const float4 vv4 = *(const float4*)(&vts[k]);
            p = fmaf(tanh_fast(x.x + bv.x), vv4.x, p);
            p = fmaf(tanh_fast(x.y + bv.y), vv4.y, p);
            p = fmaf(tanh_fast(x.z + bv.z), vv4.z, p);
            p = fmaf(tanh_fast(x.w + bv.w), vv4.w, p);
          }
          p += __shfl_xor(p, 8, 64);
          p += __shfl_xor(p, 4, 64);
          p += __shfl_xor(p, 2, 64);
          p += __shfl_xor(p, 1, 64);
          if(l16 == 0) sc[row][t] = p;
        }
      }
    }
    __syncthreads();                         // sc ready
    // ---- argmax + softmax + out + gather: wave wv<8 owns row wv ----
    if(wv < ROWS){
      const int row  = wv;
      const int brow = b0 + row;
      const float m1 = selc[row][lane] ? NEGF : sc[row][lane];
      float bestv = m1; int besti = lane;
      const int t2 = lane + 64;
      float m2 = NEGF;
      if(t2 < TT){
        m2 = selc[row][t2] ? NEGF : sc[row][t2];
        if(m2 > bestv){ bestv = m2; besti = t2; }
      }
      #pragma unroll
      for(int off=32; off>=1; off>>=1){
        const float ov = __shfl_xor(bestv, off, 64);
        const int   oi = __shfl_xor(besti, off, 64);
        if(ov > bestv || (ov == bestv && oi < besti)){ bestv = ov; besti = oi; }
      }
      float e = __expf(m1 - bestv);
      if(t2 < TT) e += __expf(m2 - bestv);
      #pragma unroll
      for(int off=32; off>=1; off>>=1) e += __shfl_xor(e, off, 64);

      float* orow = outp + (size_t)brow*(TT*TT) + (size_t)st*TT;
      __builtin_nontemporal_store(fmaxf(__expf(m1 - bestv)/e, 1e-9f), orow + lane);
      if(t2 < TT)
        __builtin_nontemporal_store(fmaxf(__expf(m2 - bestv)/e, 1e-9f), orow + t2);
      if(lane == 0) selc[row][besti] = 1;
      // gather dec_in = targets[b, sel, :] -> A x-region split3
      #pragma unroll
      for(int dd=0; dd<2; dd++){
        const int d = lane + dd*64;
        const float xv = targets[((size_t)brow*TT + besti)*DD + d];
        unsigned short th, tm, tl;
        bf16_split3(xv, th, tm, tl);
        const int idx = swA(row, d*2);
        AsH[idx] = th; AsM[idx] = tm; AsL[idx] = tl;
      }
    }
  }
}

// In-place row transform: blend1_rows <- blend1_rows @ W1^T, bf16x6 MFMA.
__global__ __launch_bounds__(128) void k_blend1(
    float* __restrict__ blend1,
    const unsigned short* __restrict__ W1H, const unsigned short* __restrict__ W1M,
    const unsigned short* __restrict__ W1L)
{
  __shared__ alignas(16) unsigned short AsH[32*264], AsM[32*264], AsL[32*264];
  const int tid  = threadIdx.x;
  const int lane = tid & 63;
  const int wv   = tid >> 6;
  const int l15  = lane & 15;
  const int l4   = lane >> 4;
  const size_t r0 = (size_t)blockIdx.x * 32;

  #pragma unroll
  for(int it=0; it<16; it++){
    const int q  = it*128 + tid;
    const int r  = q >> 6;
    const int kq = (q & 63) << 2;
    const float4 v = *(const float4*)(blend1 + (r0+r)*256 + kq);
    unsigned short h0,m0_,l0,h1,m1_,l1,h2,m2_,l2,h3,m3_,l3;
    bf16_split3(v.x,h0,m0_,l0); bf16_split3(v.y,h1,m1_,l1);
    bf16_split3(v.z,h2,m2_,l2); bf16_split3(v.w,h3,m3_,l3);
    *(ushort4*)&AsH[r*264+kq] = make_ushort4(h0,h1,h2,h3);
    *(ushort4*)&AsM[r*264+kq] = make_ushort4(m0_,m1_,m2_,m3_);
    *(ushort4*)&AsL[r*264+kq] = make_ushort4(l0,l1,l2,l3);
  }
  __syncthreads();

  f32x4 acc[16];
  #pragma unroll
  for(int s=0;s<16;s++)
    #pragma unroll
    for(int e=0;e<4;e++) acc[s][e] = 0.f;

  const int rb = wv*16;
  for(int kt=0; kt<8; kt++){
    const int k0 = kt*32;
    const short8_t aH = *(const short8_t*)&AsH[(rb+l15)*264 + k0 + l4*8];
    const short8_t aM = *(const short8_t*)&AsM[(rb+l15)*264 + k0 + l4*8];
    const short8_t aL = *(const short8_t*)&AsL[(rb+l15)*264 + k0 + l4*8];
    #pragma unroll
    for(int fn=0; fn<16; fn++){
      const int n = fn*16 + l15;
      const short8_t bH = *(const short8_t*)(W1H + (size_t)n*256 + k0 + l4*8);
      const short8_t bM = *(const short8_t*)(W1M + (size_t)n*256 + k0 + l4*8);
      const short8_t bL = *(const short8_t*)(W1L + (size_t)n*256 + k0 + l4*8);
      MFMA_X6(aH,aM,aL, bH,bM,bL, acc[fn]);
    }
  }
  #pragma unroll
  for(int fn=0; fn<16; fn++)
    #pragma unroll
    for(int r=0; r<4; r++)
      blend1[(r0 + rb + l4*4 + r)*256 + fn*16 + l15] = acc[fn][r];
}

extern "C" void kernel_launch(void* const* d_in, const int* in_sizes, int n_in,
                              void* d_out, int out_size, void* d_ws, size_t ws_size,
                              hipStream_t stream)
{
  (void)in_sizes; (void)n_in; (void)out_size; (void)ws_size;
  const float* targets  = (const float*)d_in[0];
  const float* h0       = (const float*)d_in[1];
  const float* c0       = (const float*)d_in[2];
  const float* enc_w_ih = (const float*)d_in[3];
  const float* enc_w_hh = (const float*)d_in[4];
  const float* enc_b_ih = (const float*)d_in[5];
  const float* enc_b_hh = (const float*)d_in[6];
  const float* dec_w_ih = (const float*)d_in[7];
  const float* dec_w_hh = (const float*)d_in[8];
  const float* dec_b_ih = (const float*)d_in[9];
  const float* dec_b_hh = (const float*)d_in[10];
  const float* W1       = (const float*)d_in[11];
  const float* W2       = (const float*)d_in[12];
  const float* vt       = (const float*)d_in[13];
  float* outp = (float*)d_out;

  // ---- workspace carve-up (~216 MB) ----
  float* ws      = (float*)d_ws;
  float* blend1  = ws;                               // B*T*256 fp32 (210 MB)
  char* pc = (char*)(blend1 + (size_t)BB*TT*256);
  pc = (char*)(((uintptr_t)pc + 63) & ~(uintptr_t)63);
  unsigned short* q = (unsigned short*)pc;
  const size_t WFSZ = (size_t)1024*KTOT;
  unsigned short* eWfH = q; q += WFSZ;
  unsigned short* eWfM = q; q += WFSZ;
  unsigned short* eWfL = q; q += WFSZ;
  unsigned short* dWfH = q; q += WFSZ;
  unsigned short* dWfM = q; q += WFSZ;
  unsigned short* dWfL = q; q += WFSZ;
  unsigned short* w2fH = q; q += (size_t)256*256;
  unsigned short* w2fM = q; q += (size_t)256*256;
  unsigned short* w2fL = q; q += (size_t)256*256;
  unsigned short* w1H  = q; q += (size_t)256*256;
  unsigned short* w1M  = q; q += (size_t)256*256;
  unsigned short* w1L  = q; q += (size_t)256*256;

  // ---- prep ----
  const int packGrid = (1024*KTOT + 255)/256;
  k_packW<<<packGrid, 256, 0, stream>>>(enc_w_ih, enc_w_hh, eWfH, eWfM, eWfL);
  k_packW<<<packGrid, 256, 0, stream>>>(dec_w_ih, dec_w_hh, dWfH, dWfM, dWfL);
  k_packW2<<<(256*256+255)/256, 256, 0, stream>>>(W2, w2fH, w2fM, w2fL);
  k_split3<<<(256*256+255)/256, 256, 0, stream>>>(W1, w1H, w1M, w1L, 256*256);

  // ---- encoder: 128 blocks x 16 rows, 100 steps in-block ----
  k_encoder<<<BB/RA, NTHR, 0, stream>>>(targets, eWfH, eWfM, eWfL,
                                        enc_b_ih, enc_b_hh, blend1);

  // ---- blend1 = enc_states @ W1^T, in place ----
  k_blend1<<<BB*TT/32, 128, 0, stream>>>(blend1, w1H, w1M, w1L);

  // ---- decoder: 256 blocks x 8 rows, 100 steps in-block ----
  k_decoder<<<NBLK, NTHR, 0, stream>>>(targets, dWfH, dWfM, dWfL,
                                       w2fH, w2fM, w2fL,
                                       dec_b_ih, dec_b_hh, h0, c0,
                                       vt, blend1, outp);
}

// Round 7
// 22554.128 us; speedup vs baseline: 1.3324x; 1.3324x over previous
//
#include <hip/hip_runtime.h>
#include <math.h>
#include <stdint.h>

#define BB 2048
#define TT 100
#define DD 128
#define HH 256
#define NEGF -1.0e9f

#define NBLK 256          // decoder blocks
#define ROWS 8            // valid batch rows per block (decoder)
#define RA   16           // A-tile rows (MFMA M), rows 8..15 stay zero in decoder
#define NTHR 1024         // decoder threads (16 waves)
#define EROWS 16          // encoder rows per block
#define ENTHR 512         // encoder threads (8 waves)
#define KTOT 384          // 128 (x) + 256 (h)
#define NKF  12           // K fragments (K=32 each)
#define ASTR 392          // shorts per A-LDS row (384 + 8 pad)

typedef __attribute__((ext_vector_type(8))) short short8_t;   // 8 bf16
typedef __attribute__((ext_vector_type(4))) float f32x4;

#define MFMA16(a,b,c) __builtin_amdgcn_mfma_f32_16x16x32_bf16((a),(b),(c),0,0,0)
// 6-product bf16x6 accumulate, small terms first (exact-split fp32 emulation)
#define MFMA_X6(aH,aM,aL,bH,bM,bL,acc)            \
  do{ acc = MFMA16(aM, bM, acc);                  \
      acc = MFMA16(aH, bL, acc);                  \
      acc = MFMA16(aL, bH, acc);                  \
      acc = MFMA16(aH, bM, acc);                  \
      acc = MFMA16(aM, bH, acc);                  \
      acc = MFMA16(aH, bH, acc); }while(0)

__device__ __forceinline__ float sigmoidf_(float x){ return 1.0f/(1.0f+expf(-x)); }

// fast tanh for scores only: HW exp + HW rcp. |rel err| ~1e-7.
__device__ __forceinline__ float tanh_fast(float x){
  x = fminf(15.f, fmaxf(-15.f, x));
  const float e = __expf(x + x);
  return (e - 1.f) * __builtin_amdgcn_rcpf(e + 1.f);
}

// 3-way bf16 split: x == h + m + l EXACTLY (24 mantissa bits covered).
__device__ __forceinline__ void bf16_split3(float x, unsigned short &h,
                                            unsigned short &m, unsigned short &l){
  const unsigned u = __float_as_uint(x);
  const unsigned r = u + 0x7FFFu + ((u >> 16) & 1u);
  h = (unsigned short)(r >> 16);
  const float rem = x - __uint_as_float(r & 0xFFFF0000u);
  const unsigned u2 = __float_as_uint(rem);
  const unsigned r2 = u2 + 0x7FFFu + ((u2 >> 16) & 1u);
  m = (unsigned short)(r2 >> 16);
  const float rem2 = rem - __uint_as_float(r2 & 0xFFFF0000u);
  l = (unsigned short)(__float_as_uint(rem2) >> 16);
}

__global__ __launch_bounds__(256) void k_split3(const float* __restrict__ src,
    unsigned short* __restrict__ hi, unsigned short* __restrict__ mi,
    unsigned short* __restrict__ lo, int n){
  const int i = blockIdx.x*256 + threadIdx.x;
  if(i < n){ unsigned short h,m,l; bf16_split3(src[i], h, m, l);
             hi[i]=h; mi[i]=m; lo[i]=l; }
}

// Pack {w_ih[1024][128], w_hh[1024][256]} -> fragment-ordered bf16x3:
// element i = ((f*NKF + kf)*64 + lane)*8 + e  <->  n = f*16+(lane&15),
// k = kf*32 + (lane>>4)*8 + e.  B-frag load = one coalesced 16B/lane read.
__global__ __launch_bounds__(256) void k_packW(
    const float* __restrict__ w_ih, const float* __restrict__ w_hh,
    unsigned short* __restrict__ WfH, unsigned short* __restrict__ WfM,
    unsigned short* __restrict__ WfL)
{
  const int i = blockIdx.x*256 + threadIdx.x;
  if(i >= 1024*KTOT) return;
  const int f    = i / (NKF*64*8);
  const int r1   = i % (NKF*64*8);
  const int kf   = r1 >> 9;
  const int r2   = r1 & 511;
  const int lane = r2 >> 3;
  const int e    = r2 & 7;
  const int n = f*16 + (lane & 15);
  const int k = kf*32 + (lane >> 4)*8 + e;
  const float w = (k < DD) ? w_ih[(size_t)n*DD + k] : w_hh[(size_t)n*HH + (k-DD)];
  unsigned short h,m,l; bf16_split3(w,h,m,l);
  WfH[i]=h; WfM[i]=m; WfL[i]=l;
}

// Pack W2[256][256] -> fragments: f2 in 0..15, kf2 in 0..7.
__global__ __launch_bounds__(256) void k_packW2(
    const float* __restrict__ W2,
    unsigned short* __restrict__ WfH, unsigned short* __restrict__ WfM,
    unsigned short* __restrict__ WfL)
{
  const int i = blockIdx.x*256 + threadIdx.x;
  if(i >= 256*256) return;
  const int f2   = i >> 12;          // / 4096
  const int r1   = i & 4095;
  const int kf2  = r1 >> 9;
  const int r2   = r1 & 511;
  const int lane = r2 >> 3;
  const int e    = r2 & 7;
  const int n = f2*16 + (lane & 15);
  const int k = kf2*32 + (lane >> 4)*8 + e;
  unsigned short h,m,l; bf16_split3(W2[(size_t)n*HH + k], h, m, l);
  WfH[i]=h; WfM[i]=m; WfL[i]=l;
}

// swizzled A-LDS short-index: row stride ASTR shorts, XOR bit4 of byte offset by row&7
__device__ __forceinline__ int swA(int row, int byteoff){
  return row*ASTR + (((byteoff) ^ ((row & 7) << 4)) >> 1);
}

// ============ encoder (round-4 proven config): 128 blk x 16 rows, 8 waves ====
__global__ __launch_bounds__(ENTHR) void k_encoder(
    const float* __restrict__ targets,
    const unsigned short* __restrict__ WfH, const unsigned short* __restrict__ WfM,
    const unsigned short* __restrict__ WfL,
    const float* __restrict__ bih, const float* __restrict__ bhh,
    float* __restrict__ blend1)
{
  __shared__ unsigned short AsH[EROWS*ASTR], AsM[EROWS*ASTR], AsL[EROWS*ASTR];
  const int tid = threadIdx.x;
  const int lane = tid & 63;
  const int wv = tid >> 6;                   // 0..7
  const int l15 = lane & 15, l4 = lane >> 4;
  const int b0 = blockIdx.x * EROWS;

  float bias[8];
  #pragma unroll
  for(int g=0; g<4; g++)
    #pragma unroll
    for(int c16=0; c16<2; c16++){
      const int n = g*256 + wv*32 + c16*16 + l15;
      bias[g*2+c16] = bih[n] + bhh[n];
    }
  float cst[2][4];
  #pragma unroll
  for(int a=0;a<2;a++)
    #pragma unroll
    for(int r=0;r<4;r++) cst[a][r] = 0.f;

  for(int i=tid; i<EROWS*ASTR; i+=ENTHR){ AsH[i]=0; AsM[i]=0; AsL[i]=0; }

  const int srow = tid >> 5;                 // staging: row 0..15
  const int k4   = (tid & 31) * 4;           // 4 k-elems per thread
  const int sidx = swA(srow, k4*2);

  for(int t=0; t<TT; t++){
    __syncthreads();                         // prev gates reads + epilogue done
    {                                        // stage x = targets[:, t, :] split3
      const float4 v = *(const float4*)(targets + ((size_t)(b0+srow)*TT + t)*DD + k4);
      unsigned short h0,m0_,l0,h1,m1_,l1,h2,m2_,l2,h3,m3_,l3;
      bf16_split3(v.x,h0,m0_,l0); bf16_split3(v.y,h1,m1_,l1);
      bf16_split3(v.z,h2,m2_,l2); bf16_split3(v.w,h3,m3_,l3);
      *(ushort4*)&AsH[sidx] = make_ushort4(h0,h1,h2,h3);
      *(ushort4*)&AsM[sidx] = make_ushort4(m0_,m1_,m2_,m3_);
      *(ushort4*)&AsL[sidx] = make_ushort4(l0,l1,l2,l3);
    }
    __syncthreads();
    f32x4 acc[8];
    #pragma unroll
    for(int ff=0; ff<8; ff++){
      acc[ff][0]=bias[ff]; acc[ff][1]=bias[ff]; acc[ff][2]=bias[ff]; acc[ff][3]=bias[ff];
    }
    for(int kf=0; kf<NKF; kf++){
      const int ao = swA(l15, kf*64 + l4*16);
      const short8_t aH = *(const short8_t*)&AsH[ao];
      const short8_t aM = *(const short8_t*)&AsM[ao];
      const short8_t aL = *(const short8_t*)&AsL[ao];
      #pragma unroll
      for(int g=0; g<4; g++)
        #pragma unroll
        for(int c16=0; c16<2; c16++){
          const int f = g*16 + wv*2 + c16;
          const size_t wo = ((size_t)(f*NKF + kf)*64 + lane)*8;
          const short8_t bH = *(const short8_t*)(WfH + wo);
          const short8_t bM = *(const short8_t*)(WfM + wo);
          const short8_t bL = *(const short8_t*)(WfL + wo);
          MFMA_X6(aH,aM,aL,bH,bM,bL, acc[g*2+c16]);
        }
    }
    __syncthreads();                         // A-frag reads done before h writes
    #pragma unroll
    for(int c16=0; c16<2; c16++){
      const int j = wv*32 + c16*16 + l15;
      #pragma unroll
      for(int r=0; r<4; r++){
        const int row = l4*4 + r;
        const float iv = acc[0+c16][r];
        const float fv = acc[2+c16][r];
        const float gv = acc[4+c16][r];
        const float ov = acc[6+c16][r];
        const float cn = sigmoidf_(fv)*cst[c16][r] + sigmoidf_(iv)*tanhf(gv);
        const float hn = sigmoidf_(ov)*tanhf(cn);
        cst[c16][r] = cn;
        unsigned short sh, sm_, sl;
        bf16_split3(hn, sh, sm_, sl);
        const int hi = swA(row, (128 + j)*2);
        AsH[hi] = sh; AsM[hi] = sm_; AsL[hi] = sl;
        blend1[((size_t)(b0+row)*TT + t)*256 + j] = hn;
      }
    }
  }
}

// ============ decoder: 256 blocks x 8 rows, 16 waves, nt blend1 stream ======
__global__ __launch_bounds__(NTHR) void k_decoder(
    const float* __restrict__ targets,
    const unsigned short* __restrict__ WfH, const unsigned short* __restrict__ WfM,
    const unsigned short* __restrict__ WfL,
    const unsigned short* __restrict__ W2fH, const unsigned short* __restrict__ W2fM,
    const unsigned short* __restrict__ W2fL,
    const float* __restrict__ bih, const float* __restrict__ bhh,
    const float* __restrict__ h0, const float* __restrict__ c0,
    const float* __restrict__ vt,
    const float* __restrict__ blend1,
    float* __restrict__ outp)
{
  __shared__ unsigned short AsH[RA*ASTR], AsM[RA*ASTR], AsL[RA*ASTR];
  __shared__ float b2s[ROWS*264];
  __shared__ float sc[ROWS][104];
  __shared__ float vts[256];
  __shared__ char selc[ROWS][104];
  const int tid = threadIdx.x;
  const int lane = tid & 63;
  const int wv = tid >> 6;                   // 0..15
  const int l15 = lane & 15, l4 = lane >> 4;
  const int b0 = blockIdx.x * ROWS;

  const int j = wv*16 + l15;
  float bias[4];
  #pragma unroll
  for(int g=0; g<4; g++) bias[g] = bih[g*HH + j] + bhh[g*HH + j];

  for(int i=tid; i<RA*ASTR; i+=NTHR){ AsH[i]=0; AsM[i]=0; AsL[i]=0; } // x=0 @ st0, rows 8..15 stay 0
  if(tid < 256) vts[tid] = vt[tid];
  for(int i=tid; i<ROWS*104; i+=NTHR) (&selc[0][0])[i] = 0;
  {                                          // h0 -> A h-region split3 (8 rows)
    const int row = tid >> 7;                // 0..7
    const int k2  = (tid & 127) * 2;
    const float2 v = *(const float2*)(h0 + (size_t)(b0+row)*HH + k2);
    unsigned short h0_,m0_,l0,h1,m1_,l1;
    bf16_split3(v.x,h0_,m0_,l0); bf16_split3(v.y,h1,m1_,l1);
    const int idx = swA(row, (128 + k2)*2);
    *(ushort2*)&AsH[idx] = make_ushort2(h0_,h1);
    *(ushort2*)&AsM[idx] = make_ushort2(m0_,m1_);
    *(ushort2*)&AsL[idx] = make_ushort2(l0,l1);
  }
  float cst[4];
  #pragma unroll
  for(int r=0; r<4; r++)
    cst[r] = (l4 < 2) ? c0[(size_t)(b0 + l4*4 + r)*HH + j] : 0.f;

  for(int st=0; st<TT; st++){
    __syncthreads();                         // gather/epilogue writes visible
    // ---- phase A: gates GEMM (bf16x6 MFMA) ----
    f32x4 acc[4];
    #pragma unroll
    for(int g=0; g<4; g++){
      acc[g][0]=bias[g]; acc[g][1]=bias[g]; acc[g][2]=bias[g]; acc[g][3]=bias[g];
    }
    for(int kf=0; kf<NKF; kf++){
      const int ao = swA(l15, kf*64 + l4*16);
      const short8_t aH = *(const short8_t*)&AsH[ao];
      const short8_t aM = *(const short8_t*)&AsM[ao];
      const short8_t aL = *(const short8_t*)&AsL[ao];
      #pragma unroll
      for(int g=0; g<4; g++){
        const int f = g*16 + wv;
        const size_t wo = ((size_t)(f*NKF + kf)*64 + lane)*8;
        const short8_t bH = *(const short8_t*)(WfH + wo);
        const short8_t bM = *(const short8_t*)(WfM + wo);
        const short8_t bL = *(const short8_t*)(WfL + wo);
        MFMA_X6(aH,aM,aL,bH,bM,bL, acc[g]);
      }
    }
    __syncthreads();                         // A-frag reads done before h writes
    // ---- cell epilogue: rows < 8 only; h_new split3 -> A h-region ----
    if(l4 < 2){
      #pragma unroll
      for(int r=0; r<4; r++){
        const int row = l4*4 + r;
        const float iv = acc[0][r];
        const float fv = acc[1][r];
        const float gv = acc[2][r];
        const float ov = acc[3][r];
        const float cn = sigmoidf_(fv)*cst[r] + sigmoidf_(iv)*tanhf(gv);
        const float hn = sigmoidf_(ov)*tanhf(cn);
        cst[r] = cn;
        unsigned short sh, sm_, sl;
        bf16_split3(hn, sh, sm_, sl);
        const int hi = swA(row, (128 + j)*2);
        AsH[hi] = sh; AsM[hi] = sm_; AsL[hi] = sl;
      }
    }
    __syncthreads();                         // h-region ready
    // ---- blend2 = h_new @ W2^T (bf16x6 MFMA), wave wv owns n-frag f2=wv ----
    {
      f32x4 b2acc;
      b2acc[0]=0.f; b2acc[1]=0.f; b2acc[2]=0.f; b2acc[3]=0.f;
      for(int kf2=0; kf2<8; kf2++){
        const int ao = swA(l15, (kf2+4)*64 + l4*16);
        const short8_t aH = *(const short8_t*)&AsH[ao];
        const short8_t aM = *(const short8_t*)&AsM[ao];
        const short8_t aL = *(const short8_t*)&AsL[ao];
        const size_t wo = ((size_t)(wv*8 + kf2)*64 + lane)*8;
        const short8_t bH = *(const short8_t*)(W2fH + wo);
        const short8_t bM = *(const short8_t*)(W2fM + wo);
        const short8_t bL = *(const short8_t*)(W2fL + wo);
        MFMA_X6(aH,aM,aL,bH,bM,bL, b2acc);
      }
      if(l4 < 2){
        #pragma unroll
        for(int r=0; r<4; r++)
          b2s[(l4*4 + r)*264 + wv*16 + l15] = b2acc[r];
      }
    }
    __syncthreads();                         // b2s ready
    // ---- scores: 2 waves/row, contiguous t-halves, 2-deep NT pipeline ----
    // nt loads: blend1 stream bypasses cache allocation -> weights stay
    // L2/L3-resident; blend1 HBM volume = logical 205 MB/step.
    {
      const int row  = wv >> 1;
      const int half = wv & 1;
      const int tbb  = half ? 13 : 0;        // wave0: tb 0..12, wave1: tb 13..24
      const int nit  = half ? 12 : 13;
      const int g4 = lane >> 4, l16 = lane & 15;
      const float* bl  = blend1 + (size_t)(b0+row)*TT*256;
      const float* b2p = &b2s[row*264];
      f32x4 xa0,xa1,xa2,xa3, xb0,xb1,xb2,xb3;
      {
        const size_t base = (size_t)(tbb*4 + g4)*256 + l16*4;
        xa0 = __builtin_nontemporal_load((const f32x4*)(bl + base));
        xa1 = __builtin_nontemporal_load((const f32x4*)(bl + base + 64));
        xa2 = __builtin_nontemporal_load((const f32x4*)(bl + base + 128));
        xa3 = __builtin_nontemporal_load((const f32x4*)(bl + base + 192));
      }
      for(int i=0; i<nit; i++){
        if(i+1 < nit){
          const size_t base = (size_t)((tbb+i+1)*4 + g4)*256 + l16*4;
          xb0 = __builtin_nontemporal_load((const f32x4*)(bl + base));
          xb1 = __builtin_nontemporal_load((const f32x4*)(bl + base + 64));
          xb2 = __builtin_nontemporal_load((const f32x4*)(bl + base + 128));
          xb3 = __builtin_nontemporal_load((const f32x4*)(bl + base + 192));
        }
        const int t = (tbb+i)*4 + g4;
        float p = 0.f;
        {
          const int k = l16*4;
          const f32x4 bv = *(const f32x4*)(b2p + k);
          const f32x4 vv = *(const f32x4*)(&vts[k]);
          p = fmaf(tanh_fast(xa0[0]+bv[0]), vv[0], p);
          p = fmaf(tanh_fast(xa0[1]+bv[1]), vv[1], p);
          p = fmaf(tanh_fast(xa0[2]+bv[2]), vv[2], p);
          p = fmaf(tanh_fast(xa0[3]+bv[3]), vv[3], p);
        }
        {
          const int k = 64 + l16*4;
          const f32x4 bv = *(const f32x4*)(b2p + k);
          const f32x4 vv = *(const f32x4*)(&vts[k]);
          p = fmaf(tanh_fast(xa1[0]+bv[0]), vv[0], p);
          p = fmaf(tanh_fast(xa1[1]+bv[1]), vv[1], p);
          p = fmaf(tanh_fast(xa1[2]+bv[2]), vv[2], p);
          p = fmaf(tanh_fast(xa1[3]+bv[3]), vv[3], p);
        }
        {
          const int k = 128 + l16*4;
          const f32x4 bv = *(const f32x4*)(b2p + k);
          const f32x4 vv = *(const f32x4*)(&vts[k]);
          p = fmaf(tanh_fast(xa2[0]+bv[0]), vv[0], p);
          p = fmaf(tanh_fast(xa2[1]+bv[1]), vv[1], p);
          p = fmaf(tanh_fast(xa2[2]+bv[2]), vv[2], p);
          p = fmaf(tanh_fast(xa2[3]+bv[3]), vv[3], p);
        }
        {
          const int k = 192 + l16*4;
          const f32x4 bv = *(const f32x4*)(b2p + k);
          const f32x4 vv = *(const f32x4*)(&vts[k]);
          p = fmaf(tanh_fast(xa3[0]+bv[0]), vv[0], p);
          p = fmaf(tanh_fast(xa3[1]+bv[1]), vv[1], p);
          p = fmaf(tanh_fast(xa3[2]+bv[2]), vv[2], p);
          p = fmaf(tanh_fast(xa3[3]+bv[3]), vv[3], p);
        }
        p += __shfl_xor(p, 8, 64);
        p += __shfl_xor(p, 4, 64);
        p += __shfl_xor(p, 2, 64);
        p += __shfl_xor(p, 1, 64);
        if(l16 == 0) sc[row][t] = p;
        xa0 = xb0; xa1 = xb1; xa2 = xb2; xa3 = xb3;
      }
    }
    __syncthreads();                         // sc ready
    // ---- argmax + softmax + out + gather: wave wv<8 owns row wv ----
    if(wv < ROWS){
      const int row  = wv;
      const int brow = b0 + row;
      const float m1 = selc[row][lane] ? NEGF : sc[row][lane];
      float bestv = m1; int besti = lane;
      const int t2 = lane + 64;
      float m2 = NEGF;
      if(t2 < TT){
        m2 = selc[row][t2] ? NEGF : sc[row][t2];
        if(m2 > bestv){ bestv = m2; besti = t2; }
      }
      #pragma unroll
      for(int off=32; off>=1; off>>=1){
        const float ov = __shfl_xor(bestv, off, 64);
        const int   oi = __shfl_xor(besti, off, 64);
        if(ov > bestv || (ov == bestv && oi < besti)){ bestv = ov; besti = oi; }
      }
      float e = __expf(m1 - bestv);
      if(t2 < TT) e += __expf(m2 - bestv);
      #pragma unroll
      for(int off=32; off>=1; off>>=1) e += __shfl_xor(e, off, 64);

      float* orow = outp + (size_t)brow*(TT*TT) + (size_t)st*TT;
      __builtin_nontemporal_store(fmaxf(__expf(m1 - bestv)/e, 1e-9f), orow + lane);
      if(t2 < TT)
        __builtin_nontemporal_store(fmaxf(__expf(m2 - bestv)/e, 1e-9f), orow + t2);
      if(lane == 0) selc[row][besti] = 1;
      // gather dec_in = targets[b, sel, :] -> A x-region split3
      #pragma unroll
      for(int dd=0; dd<2; dd++){
        const int d = lane + dd*64;
        const float xv = targets[((size_t)brow*TT + besti)*DD + d];
        unsigned short th, tm, tl;
        bf16_split3(xv, th, tm, tl);
        const int idx = swA(row, d*2);
        AsH[idx] = th; AsM[idx] = tm; AsL[idx] = tl;
      }
    }
  }
}

// In-place row transform: blend1_rows <- blend1_rows @ W1^T, bf16x6 MFMA.
__global__ __launch_bounds__(128) void k_blend1(
    float* __restrict__ blend1,
    const unsigned short* __restrict__ W1H, const unsigned short* __restrict__ W1M,
    const unsigned short* __restrict__ W1L)
{
  __shared__ alignas(16) unsigned short AsH[32*264], AsM[32*264], AsL[32*264];
  const int tid  = threadIdx.x;
  const int lane = tid & 63;
  const int wv   = tid >> 6;
  const int l15  = lane & 15;
  const int l4   = lane >> 4;
  const size_t r0 = (size_t)blockIdx.x * 32;

  #pragma unroll
  for(int it=0; it<16; it++){
    const int q  = it*128 + tid;
    const int r  = q >> 6;
    const int kq = (q & 63) << 2;
    const float4 v = *(const float4*)(blend1 + (r0+r)*256 + kq);
    unsigned short h0,m0_,l0,h1,m1_,l1,h2,m2_,l2,h3,m3_,l3;
    bf16_split3(v.x,h0,m0_,l0); bf16_split3(v.y,h1,m1_,l1);
    bf16_split3(v.z,h2,m2_,l2); bf16_split3(v.w,h3,m3_,l3);
    *(ushort4*)&AsH[r*264+kq] = make_ushort4(h0,h1,h2,h3);
    *(ushort4*)&AsM[r*264+kq] = make_ushort4(m0_,m1_,m2_,m3_);
    *(ushort4*)&AsL[r*264+kq] = make_ushort4(l0,l1,l2,l3);
  }
  __syncthreads();

  f32x4 acc[16];
  #pragma unroll
  for(int s=0;s<16;s++)
    #pragma unroll
    for(int e=0;e<4;e++) acc[s][e] = 0.f;

  const int rb = wv*16;
  for(int kt=0; kt<8; kt++){
    const int k0 = kt*32;
    const short8_t aH = *(const short8_t*)&AsH[(rb+l15)*264 + k0 + l4*8];
    const short8_t aM = *(const short8_t*)&AsM[(rb+l15)*264 + k0 + l4*8];
    const short8_t aL = *(const short8_t*)&AsL[(rb+l15)*264 + k0 + l4*8];
    #pragma unroll
    for(int fn=0; fn<16; fn++){
      const int n = fn*16 + l15;
      const short8_t bH = *(const short8_t*)(W1H + (size_t)n*256 + k0 + l4*8);
      const short8_t bM = *(const short8_t*)(W1M + (size_t)n*256 + k0 + l4*8);
      const short8_t bL = *(const short8_t*)(W1L + (size_t)n*256 + k0 + l4*8);
      MFMA_X6(aH,aM,aL, bH,bM,bL, acc[fn]);
    }
  }
  #pragma unroll
  for(int fn=0; fn<16; fn++)
    #pragma unroll
    for(int r=0; r<4; r++)
      blend1[(r0 + rb + l4*4 + r)*256 + fn*16 + l15] = acc[fn][r];
}

extern "C" void kernel_launch(void* const* d_in, const int* in_sizes, int n_in,
                              void* d_out, int out_size, void* d_ws, size_t ws_size,
                              hipStream_t stream)
{
  (void)in_sizes; (void)n_in; (void)out_size; (void)ws_size;
  const float* targets  = (const float*)d_in[0];
  const float* h0       = (const float*)d_in[1];
  const float* c0       = (const float*)d_in[2];
  const float* enc_w_ih = (const float*)d_in[3];
  const float* enc_w_hh = (const float*)d_in[4];
  const float* enc_b_ih = (const float*)d_in[5];
  const float* enc_b_hh = (const float*)d_in[6];
  const float* dec_w_ih = (const float*)d_in[7];
  const float* dec_w_hh = (const float*)d_in[8];
  const float* dec_b_ih = (const float*)d_in[9];
  const float* dec_b_hh = (const float*)d_in[10];
  const float* W1       = (const float*)d_in[11];
  const float* W2       = (const float*)d_in[12];
  const float* vt       = (const float*)d_in[13];
  float* outp = (float*)d_out;

  // ---- workspace carve-up (~216 MB) ----
  float* ws      = (float*)d_ws;
  float* blend1  = ws;                               // B*T*256 fp32 (210 MB)
  char* pc = (char*)(blend1 + (size_t)BB*TT*256);
  pc = (char*)(((uintptr_t)pc + 63) & ~(uintptr_t)63);
  unsigned short* q = (unsigned short*)pc;
  const size_t WFSZ = (size_t)1024*KTOT;
  unsigned short* eWfH = q; q += WFSZ;
  unsigned short* eWfM = q; q += WFSZ;
  unsigned short* eWfL = q; q += WFSZ;
  unsigned short* dWfH = q; q += WFSZ;
  unsigned short* dWfM = q; q += WFSZ;
  unsigned short* dWfL = q; q += WFSZ;
  unsigned short* w2fH = q; q += (size_t)256*256;
  unsigned short* w2fM = q; q += (size_t)256*256;
  unsigned short* w2fL = q; q += (size_t)256*256;
  unsigned short* w1H  = q; q += (size_t)256*256;
  unsigned short* w1M  = q; q += (size_t)256*256;
  unsigned short* w1L  = q; q += (size_t)256*256;

  // ---- prep ----
  const int packGrid = (1024*KTOT + 255)/256;
  k_packW<<<packGrid, 256, 0, stream>>>(enc_w_ih, enc_w_hh, eWfH, eWfM, eWfL);
  k_packW<<<packGrid, 256, 0, stream>>>(dec_w_ih, dec_w_hh, dWfH, dWfM, dWfL);
  k_packW2<<<(256*256+255)/256, 256, 0, stream>>>(W2, w2fH, w2fM, w2fL);
  k_split3<<<(256*256+255)/256, 256, 0, stream>>>(W1, w1H, w1M, w1L, 256*256);

  // ---- encoder: 128 blocks x 16 rows, 100 steps in-block (round-4 config) ----
  k_encoder<<<BB/EROWS, ENTHR, 0, stream>>>(targets, eWfH, eWfM, eWfL,
                                            enc_b_ih, enc_b_hh, blend1);

  // ---- blend1 = enc_states @ W1^T, in place ----
  k_blend1<<<BB*TT/32, 128, 0, stream>>>(blend1, w1H, w1M, w1L);

  // ---- decoder: 256 blocks x 8 rows, 100 steps in-block ----
  k_decoder<<<NBLK, NTHR, 0, stream>>>(targets, dWfH, dWfM, dWfL,
                                       w2fH, w2fM, w2fL,
                                       dec_b_ih, dec_b_hh, h0, c0,
                                       vt, blend1, outp);
}

// Round 8
// 22531.712 us; speedup vs baseline: 1.3338x; 1.0010x over previous
//
#include <hip/hip_runtime.h>
#include <math.h>
#include <stdint.h>

#define BB 2048
#define TT 100
#define DD 128
#define HH 256
#define NEGF -1.0e9f

#define NBLK 256          // decoder blocks
#define ROWS 8            // valid batch rows per block (decoder)
#define RA   16           // A-tile rows (MFMA M), rows 8..15 stay zero in decoder
#define NTHR 1024         // decoder threads (16 waves)
#define EROWS 16          // encoder rows per block
#define ENTHR 512         // encoder threads (8 waves)
#define KTOT 384          // 128 (x) + 256 (h)
#define NKF  12           // K fragments (K=32 each)
#define ASTR 392          // shorts per A-LDS row (384 + 8 pad)
#define DREP 8            // decoder weight copies (one per XCD)
#define EREP 4            // encoder weight copies

typedef __attribute__((ext_vector_type(8))) short short8_t;   // 8 bf16
typedef __attribute__((ext_vector_type(4))) float f32x4;

#define MFMA16(a,b,c) __builtin_amdgcn_mfma_f32_16x16x32_bf16((a),(b),(c),0,0,0)
// 6-product bf16x6 accumulate, small terms first (exact-split fp32 emulation)
#define MFMA_X6(aH,aM,aL,bH,bM,bL,acc)            \
  do{ acc = MFMA16(aM, bM, acc);                  \
      acc = MFMA16(aH, bL, acc);                  \
      acc = MFMA16(aL, bH, acc);                  \
      acc = MFMA16(aH, bM, acc);                  \
      acc = MFMA16(aM, bH, acc);                  \
      acc = MFMA16(aH, bH, acc); }while(0)

__device__ __forceinline__ float sigmoidf_(float x){ return 1.0f/(1.0f+expf(-x)); }

// fast tanh for scores only: HW exp + HW rcp. |rel err| ~1e-7.
__device__ __forceinline__ float tanh_fast(float x){
  x = fminf(15.f, fmaxf(-15.f, x));
  const float e = __expf(x + x);
  return (e - 1.f) * __builtin_amdgcn_rcpf(e + 1.f);
}

// 3-way bf16 split: x == h + m + l EXACTLY (24 mantissa bits covered).
__device__ __forceinline__ void bf16_split3(float x, unsigned short &h,
                                            unsigned short &m, unsigned short &l){
  const unsigned u = __float_as_uint(x);
  const unsigned r = u + 0x7FFFu + ((u >> 16) & 1u);
  h = (unsigned short)(r >> 16);
  const float rem = x - __uint_as_float(r & 0xFFFF0000u);
  const unsigned u2 = __float_as_uint(rem);
  const unsigned r2 = u2 + 0x7FFFu + ((u2 >> 16) & 1u);
  m = (unsigned short)(r2 >> 16);
  const float rem2 = rem - __uint_as_float(r2 & 0xFFFF0000u);
  l = (unsigned short)(__float_as_uint(rem2) >> 16);
}

__global__ __launch_bounds__(256) void k_split3(const float* __restrict__ src,
    unsigned short* __restrict__ hi, unsigned short* __restrict__ mi,
    unsigned short* __restrict__ lo, int n){
  const int i = blockIdx.x*256 + threadIdx.x;
  if(i < n){ unsigned short h,m,l; bf16_split3(src[i], h, m, l);
             hi[i]=h; mi[i]=m; lo[i]=l; }
}

// Pack {w_ih[1024][128], w_hh[1024][256]} -> fragment-ordered bf16x3, NCOPY copies:
// element i = ((f*NKF + kf)*64 + lane)*8 + e  <->  n = f*16+(lane&15),
// k = kf*32 + (lane>>4)*8 + e.  B-frag load = one coalesced 16B/lane read.
__global__ __launch_bounds__(256) void k_packW(
    const float* __restrict__ w_ih, const float* __restrict__ w_hh,
    unsigned short* __restrict__ WfH, unsigned short* __restrict__ WfM,
    unsigned short* __restrict__ WfL, int ncopy)
{
  const int i = blockIdx.x*256 + threadIdx.x;
  if(i >= 1024*KTOT) return;
  const int f    = i / (NKF*64*8);
  const int r1   = i % (NKF*64*8);
  const int kf   = r1 >> 9;
  const int r2   = r1 & 511;
  const int lane = r2 >> 3;
  const int e    = r2 & 7;
  const int n = f*16 + (lane & 15);
  const int k = kf*32 + (lane >> 4)*8 + e;
  const float w = (k < DD) ? w_ih[(size_t)n*DD + k] : w_hh[(size_t)n*HH + (k-DD)];
  unsigned short h,m,l; bf16_split3(w,h,m,l);
  for(int c=0; c<ncopy; c++){
    const size_t o = (size_t)c*(1024*KTOT) + i;
    WfH[o]=h; WfM[o]=m; WfL[o]=l;
  }
}

// Pack W2[256][256] -> fragments (f2 0..15, kf2 0..7), DREP copies.
__global__ __launch_bounds__(256) void k_packW2(
    const float* __restrict__ W2,
    unsigned short* __restrict__ WfH, unsigned short* __restrict__ WfM,
    unsigned short* __restrict__ WfL)
{
  const int i = blockIdx.x*256 + threadIdx.x;
  if(i >= 256*256) return;
  const int f2   = i >> 12;
  const int r1   = i & 4095;
  const int kf2  = r1 >> 9;
  const int r2   = r1 & 511;
  const int lane = r2 >> 3;
  const int e    = r2 & 7;
  const int n = f2*16 + (lane & 15);
  const int k = kf2*32 + (lane >> 4)*8 + e;
  unsigned short h,m,l; bf16_split3(W2[(size_t)n*HH + k], h, m, l);
  for(int c=0; c<DREP; c++){
    const size_t o = (size_t)c*(256*256) + i;
    WfH[o]=h; WfM[o]=m; WfL[o]=l;
  }
}

// swizzled A-LDS short-index: row stride ASTR shorts, XOR bit4 of byte offset by row&7
__device__ __forceinline__ int swA(int row, int byteoff){
  return row*ASTR + (((byteoff) ^ ((row & 7) << 4)) >> 1);
}

// ============ encoder: 128 blk x 16 rows, 8 waves, 4x-replicated weights =====
__global__ __launch_bounds__(ENTHR) void k_encoder(
    const float* __restrict__ targets,
    const unsigned short* __restrict__ WfH0, const unsigned short* __restrict__ WfM0,
    const unsigned short* __restrict__ WfL0,
    const float* __restrict__ bih, const float* __restrict__ bhh,
    float* __restrict__ blend1)
{
  __shared__ unsigned short AsH[EROWS*ASTR], AsM[EROWS*ASTR], AsL[EROWS*ASTR];
  const int tid = threadIdx.x;
  const int lane = tid & 63;
  const int wv = tid >> 6;                   // 0..7
  const int l15 = lane & 15, l4 = lane >> 4;
  const int b0 = blockIdx.x * EROWS;
  const size_t wrep = (size_t)(blockIdx.x & (EREP-1)) * (1024*KTOT);
  const unsigned short* __restrict__ WfH = WfH0 + wrep;
  const unsigned short* __restrict__ WfM = WfM0 + wrep;
  const unsigned short* __restrict__ WfL = WfL0 + wrep;

  float bias[8];
  #pragma unroll
  for(int g=0; g<4; g++)
    #pragma unroll
    for(int c16=0; c16<2; c16++){
      const int n = g*256 + wv*32 + c16*16 + l15;
      bias[g*2+c16] = bih[n] + bhh[n];
    }
  float cst[2][4];
  #pragma unroll
  for(int a=0;a<2;a++)
    #pragma unroll
    for(int r=0;r<4;r++) cst[a][r] = 0.f;

  for(int i=tid; i<EROWS*ASTR; i+=ENTHR){ AsH[i]=0; AsM[i]=0; AsL[i]=0; }

  const int srow = tid >> 5;                 // staging: row 0..15
  const int k4   = (tid & 31) * 4;           // 4 k-elems per thread
  const int sidx = swA(srow, k4*2);

  for(int t=0; t<TT; t++){
    __syncthreads();                         // prev gates reads + epilogue done
    {                                        // stage x = targets[:, t, :] split3
      const float4 v = *(const float4*)(targets + ((size_t)(b0+srow)*TT + t)*DD + k4);
      unsigned short h0,m0_,l0,h1,m1_,l1,h2,m2_,l2,h3,m3_,l3;
      bf16_split3(v.x,h0,m0_,l0); bf16_split3(v.y,h1,m1_,l1);
      bf16_split3(v.z,h2,m2_,l2); bf16_split3(v.w,h3,m3_,l3);
      *(ushort4*)&AsH[sidx] = make_ushort4(h0,h1,h2,h3);
      *(ushort4*)&AsM[sidx] = make_ushort4(m0_,m1_,m2_,m3_);
      *(ushort4*)&AsL[sidx] = make_ushort4(l0,l1,l2,l3);
    }
    __syncthreads();
    f32x4 acc[8];
    #pragma unroll
    for(int ff=0; ff<8; ff++){
      acc[ff][0]=bias[ff]; acc[ff][1]=bias[ff]; acc[ff][2]=bias[ff]; acc[ff][3]=bias[ff];
    }
    for(int kf=0; kf<NKF; kf++){
      const int ao = swA(l15, kf*64 + l4*16);
      const short8_t aH = *(const short8_t*)&AsH[ao];
      const short8_t aM = *(const short8_t*)&AsM[ao];
      const short8_t aL = *(const short8_t*)&AsL[ao];
      #pragma unroll
      for(int g=0; g<4; g++)
        #pragma unroll
        for(int c16=0; c16<2; c16++){
          const int f = g*16 + wv*2 + c16;
          const size_t wo = ((size_t)(f*NKF + kf)*64 + lane)*8;
          const short8_t bH = *(const short8_t*)(WfH + wo);
          const short8_t bM = *(const short8_t*)(WfM + wo);
          const short8_t bL = *(const short8_t*)(WfL + wo);
          MFMA_X6(aH,aM,aL,bH,bM,bL, acc[g*2+c16]);
        }
    }
    __syncthreads();                         // A-frag reads done before h writes
    #pragma unroll
    for(int c16=0; c16<2; c16++){
      const int j = wv*32 + c16*16 + l15;
      #pragma unroll
      for(int r=0; r<4; r++){
        const int row = l4*4 + r;
        const float iv = acc[0+c16][r];
        const float fv = acc[2+c16][r];
        const float gv = acc[4+c16][r];
        const float ov = acc[6+c16][r];
        const float cn = sigmoidf_(fv)*cst[c16][r] + sigmoidf_(iv)*tanhf(gv);
        const float hn = sigmoidf_(ov)*tanhf(cn);
        cst[c16][r] = cn;
        unsigned short sh, sm_, sl;
        bf16_split3(hn, sh, sm_, sl);
        const int hi = swA(row, (128 + j)*2);
        AsH[hi] = sh; AsM[hi] = sm_; AsL[hi] = sl;
        blend1[((size_t)(b0+row)*TT + t)*256 + j] = hn;
      }
    }
  }
}

// ============ decoder: 256 blk x 8 rows, 16 waves, 8x-replicated weights =====
__global__ __launch_bounds__(NTHR) void k_decoder(
    const float* __restrict__ targets,
    const unsigned short* __restrict__ WfH0, const unsigned short* __restrict__ WfM0,
    const unsigned short* __restrict__ WfL0,
    const unsigned short* __restrict__ W2fH0, const unsigned short* __restrict__ W2fM0,
    const unsigned short* __restrict__ W2fL0,
    const float* __restrict__ bih, const float* __restrict__ bhh,
    const float* __restrict__ h0, const float* __restrict__ c0,
    const float* __restrict__ vt,
    const float* __restrict__ blend1,
    float* __restrict__ outp)
{
  __shared__ unsigned short AsH[RA*ASTR], AsM[RA*ASTR], AsL[RA*ASTR];
  __shared__ float b2s[ROWS*264];
  __shared__ float sc[ROWS][104];
  __shared__ float vts[256];
  __shared__ char selc[ROWS][104];
  const int tid = threadIdx.x;
  const int lane = tid & 63;
  const int wv = tid >> 6;                   // 0..15
  const int l15 = lane & 15, l4 = lane >> 4;
  const int b0 = blockIdx.x * ROWS;
  const size_t wrep  = (size_t)(blockIdx.x & (DREP-1)) * (1024*KTOT);
  const size_t w2rep = (size_t)(blockIdx.x & (DREP-1)) * (256*256);
  const unsigned short* __restrict__ WfH = WfH0 + wrep;
  const unsigned short* __restrict__ WfM = WfM0 + wrep;
  const unsigned short* __restrict__ WfL = WfL0 + wrep;
  const unsigned short* __restrict__ W2fH = W2fH0 + w2rep;
  const unsigned short* __restrict__ W2fM = W2fM0 + w2rep;
  const unsigned short* __restrict__ W2fL = W2fL0 + w2rep;

  const int j = wv*16 + l15;
  float bias[4];
  #pragma unroll
  for(int g=0; g<4; g++) bias[g] = bih[g*HH + j] + bhh[g*HH + j];

  for(int i=tid; i<RA*ASTR; i+=NTHR){ AsH[i]=0; AsM[i]=0; AsL[i]=0; } // x=0 @ st0, rows 8..15 stay 0
  if(tid < 256) vts[tid] = vt[tid];
  for(int i=tid; i<ROWS*104; i+=NTHR) (&selc[0][0])[i] = 0;
  {                                          // h0 -> A h-region split3 (8 rows)
    const int row = tid >> 7;                // 0..7
    const int k2  = (tid & 127) * 2;
    const float2 v = *(const float2*)(h0 + (size_t)(b0+row)*HH + k2);
    unsigned short h0_,m0_,l0,h1,m1_,l1;
    bf16_split3(v.x,h0_,m0_,l0); bf16_split3(v.y,h1,m1_,l1);
    const int idx = swA(row, (128 + k2)*2);
    *(ushort2*)&AsH[idx] = make_ushort2(h0_,h1);
    *(ushort2*)&AsM[idx] = make_ushort2(m0_,m1_);
    *(ushort2*)&AsL[idx] = make_ushort2(l0,l1);
  }
  float cst[4];
  #pragma unroll
  for(int r=0; r<4; r++)
    cst[r] = (l4 < 2) ? c0[(size_t)(b0 + l4*4 + r)*HH + j] : 0.f;

  for(int st=0; st<TT; st++){
    __syncthreads();                         // gather/epilogue writes visible
    // ---- phase A: gates GEMM (bf16x6 MFMA) ----
    f32x4 acc[4];
    #pragma unroll
    for(int g=0; g<4; g++){
      acc[g][0]=bias[g]; acc[g][1]=bias[g]; acc[g][2]=bias[g]; acc[g][3]=bias[g];
    }
    for(int kf=0; kf<NKF; kf++){
      const int ao = swA(l15, kf*64 + l4*16);
      const short8_t aH = *(const short8_t*)&AsH[ao];
      const short8_t aM = *(const short8_t*)&AsM[ao];
      const short8_t aL = *(const short8_t*)&AsL[ao];
      #pragma unroll
      for(int g=0; g<4; g++){
        const int f = g*16 + wv;
        const size_t wo = ((size_t)(f*NKF + kf)*64 + lane)*8;
        const short8_t bH = *(const short8_t*)(WfH + wo);
        const short8_t bM = *(const short8_t*)(WfM + wo);
        const short8_t bL = *(const short8_t*)(WfL + wo);
        MFMA_X6(aH,aM,aL,bH,bM,bL, acc[g]);
      }
    }
    __syncthreads();                         // A-frag reads done before h writes
    // ---- cell epilogue: rows < 8 only; h_new split3 -> A h-region ----
    if(l4 < 2){
      #pragma unroll
      for(int r=0; r<4; r++){
        const int row = l4*4 + r;
        const float iv = acc[0][r];
        const float fv = acc[1][r];
        const float gv = acc[2][r];
        const float ov = acc[3][r];
        const float cn = sigmoidf_(fv)*cst[r] + sigmoidf_(iv)*tanhf(gv);
        const float hn = sigmoidf_(ov)*tanhf(cn);
        cst[r] = cn;
        unsigned short sh, sm_, sl;
        bf16_split3(hn, sh, sm_, sl);
        const int hi = swA(row, (128 + j)*2);
        AsH[hi] = sh; AsM[hi] = sm_; AsL[hi] = sl;
      }
    }
    __syncthreads();                         // h-region ready
    // ---- blend2 = h_new @ W2^T (bf16x6 MFMA), wave wv owns n-frag f2=wv ----
    {
      f32x4 b2acc;
      b2acc[0]=0.f; b2acc[1]=0.f; b2acc[2]=0.f; b2acc[3]=0.f;
      for(int kf2=0; kf2<8; kf2++){
        const int ao = swA(l15, (kf2+4)*64 + l4*16);
        const short8_t aH = *(const short8_t*)&AsH[ao];
        const short8_t aM = *(const short8_t*)&AsM[ao];
        const short8_t aL = *(const short8_t*)&AsL[ao];
        const size_t wo = ((size_t)(wv*8 + kf2)*64 + lane)*8;
        const short8_t bH = *(const short8_t*)(W2fH + wo);
        const short8_t bM = *(const short8_t*)(W2fM + wo);
        const short8_t bL = *(const short8_t*)(W2fL + wo);
        MFMA_X6(aH,aM,aL,bH,bM,bL, b2acc);
      }
      if(l4 < 2){
        #pragma unroll
        for(int r=0; r<4; r++)
          b2s[(l4*4 + r)*264 + wv*16 + l15] = b2acc[r];
      }
    }
    __syncthreads();                         // b2s ready
    // ---- scores: 2 waves/row, contiguous t-halves, 2-deep NT pipeline ----
    {
      const int row  = wv >> 1;
      const int half = wv & 1;
      const int tbb  = half ? 13 : 0;        // wave0: tb 0..12, wave1: tb 13..24
      const int nit  = half ? 12 : 13;
      const int g4 = lane >> 4, l16 = lane & 15;
      const float* bl  = blend1 + (size_t)(b0+row)*TT*256;
      const float* b2p = &b2s[row*264];
      f32x4 xa0,xa1,xa2,xa3, xb0,xb1,xb2,xb3;
      {
        const size_t base = (size_t)(tbb*4 + g4)*256 + l16*4;
        xa0 = __builtin_nontemporal_load((const f32x4*)(bl + base));
        xa1 = __builtin_nontemporal_load((const f32x4*)(bl + base + 64));
        xa2 = __builtin_nontemporal_load((const f32x4*)(bl + base + 128));
        xa3 = __builtin_nontemporal_load((const f32x4*)(bl + base + 192));
      }
      for(int i=0; i<nit; i++){
        if(i+1 < nit){
          const size_t base = (size_t)((tbb+i+1)*4 + g4)*256 + l16*4;
          xb0 = __builtin_nontemporal_load((const f32x4*)(bl + base));
          xb1 = __builtin_nontemporal_load((const f32x4*)(bl + base + 64));
          xb2 = __builtin_nontemporal_load((const f32x4*)(bl + base + 128));
          xb3 = __builtin_nontemporal_load((const f32x4*)(bl + base + 192));
        }
        const int t = (tbb+i)*4 + g4;
        float p = 0.f;
        {
          const int k = l16*4;
          const f32x4 bv = *(const f32x4*)(b2p + k);
          const f32x4 vv = *(const f32x4*)(&vts[k]);
          p = fmaf(tanh_fast(xa0[0]+bv[0]), vv[0], p);
          p = fmaf(tanh_fast(xa0[1]+bv[1]), vv[1], p);
          p = fmaf(tanh_fast(xa0[2]+bv[2]), vv[2], p);
          p = fmaf(tanh_fast(xa0[3]+bv[3]), vv[3], p);
        }
        {
          const int k = 64 + l16*4;
          const f32x4 bv = *(const f32x4*)(b2p + k);
          const f32x4 vv = *(const f32x4*)(&vts[k]);
          p = fmaf(tanh_fast(xa1[0]+bv[0]), vv[0], p);
          p = fmaf(tanh_fast(xa1[1]+bv[1]), vv[1], p);
          p = fmaf(tanh_fast(xa1[2]+bv[2]), vv[2], p);
          p = fmaf(tanh_fast(xa1[3]+bv[3]), vv[3], p);
        }
        {
          const int k = 128 + l16*4;
          const f32x4 bv = *(const f32x4*)(b2p + k);
          const f32x4 vv = *(const f32x4*)(&vts[k]);
          p = fmaf(tanh_fast(xa2[0]+bv[0]), vv[0], p);
          p = fmaf(tanh_fast(xa2[1]+bv[1]), vv[1], p);
          p = fmaf(tanh_fast(xa2[2]+bv[2]), vv[2], p);
          p = fmaf(tanh_fast(xa2[3]+bv[3]), vv[3], p);
        }
        {
          const int k = 192 + l16*4;
          const f32x4 bv = *(const f32x4*)(b2p + k);
          const f32x4 vv = *(const f32x4*)(&vts[k]);
          p = fmaf(tanh_fast(xa3[0]+bv[0]), vv[0], p);
          p = fmaf(tanh_fast(xa3[1]+bv[1]), vv[1], p);
          p = fmaf(tanh_fast(xa3[2]+bv[2]), vv[2], p);
          p = fmaf(tanh_fast(xa3[3]+bv[3]), vv[3], p);
        }
        p += __shfl_xor(p, 8, 64);
        p += __shfl_xor(p, 4, 64);
        p += __shfl_xor(p, 2, 64);
        p += __shfl_xor(p, 1, 64);
        if(l16 == 0) sc[row][t] = p;
        xa0 = xb0; xa1 = xb1; xa2 = xb2; xa3 = xb3;
      }
    }
    __syncthreads();                         // sc ready
    // ---- argmax + softmax + out + gather: wave wv<8 owns row wv ----
    if(wv < ROWS){
      const int row  = wv;
      const int brow = b0 + row;
      const float m1 = selc[row][lane] ? NEGF : sc[row][lane];
      float bestv = m1; int besti = lane;
      const int t2 = lane + 64;
      float m2 = NEGF;
      if(t2 < TT){
        m2 = selc[row][t2] ? NEGF : sc[row][t2];
        if(m2 > bestv){ bestv = m2; besti = t2; }
      }
      #pragma unroll
      for(int off=32; off>=1; off>>=1){
        const float ov = __shfl_xor(bestv, off, 64);
        const int   oi = __shfl_xor(besti, off, 64);
        if(ov > bestv || (ov == bestv && oi < besti)){ bestv = ov; besti = oi; }
      }
      float e = __expf(m1 - bestv);
      if(t2 < TT) e += __expf(m2 - bestv);
      #pragma unroll
      for(int off=32; off>=1; off>>=1) e += __shfl_xor(e, off, 64);

      float* orow = outp + (size_t)brow*(TT*TT) + (size_t)st*TT;
      __builtin_nontemporal_store(fmaxf(__expf(m1 - bestv)/e, 1e-9f), orow + lane);
      if(t2 < TT)
        __builtin_nontemporal_store(fmaxf(__expf(m2 - bestv)/e, 1e-9f), orow + t2);
      if(lane == 0) selc[row][besti] = 1;
      // gather dec_in = targets[b, sel, :] -> A x-region split3
      #pragma unroll
      for(int dd=0; dd<2; dd++){
        const int d = lane + dd*64;
        const float xv = targets[((size_t)brow*TT + besti)*DD + d];
        unsigned short th, tm, tl;
        bf16_split3(xv, th, tm, tl);
        const int idx = swA(row, d*2);
        AsH[idx] = th; AsM[idx] = tm; AsL[idx] = tl;
      }
    }
  }
}

// In-place row transform: blend1_rows <- blend1_rows @ W1^T, bf16x6 MFMA.
__global__ __launch_bounds__(128) void k_blend1(
    float* __restrict__ blend1,
    const unsigned short* __restrict__ W1H, const unsigned short* __restrict__ W1M,
    const unsigned short* __restrict__ W1L)
{
  __shared__ alignas(16) unsigned short AsH[32*264], AsM[32*264], AsL[32*264];
  const int tid  = threadIdx.x;
  const int lane = tid & 63;
  const int wv   = tid >> 6;
  const int l15  = lane & 15;
  const int l4   = lane >> 4;
  const size_t r0 = (size_t)blockIdx.x * 32;

  #pragma unroll
  for(int it=0; it<16; it++){
    const int q  = it*128 + tid;
    const int r  = q >> 6;
    const int kq = (q & 63) << 2;
    const float4 v = *(const float4*)(blend1 + (r0+r)*256 + kq);
    unsigned short h0,m0_,l0,h1,m1_,l1,h2,m2_,l2,h3,m3_,l3;
    bf16_split3(v.x,h0,m0_,l0); bf16_split3(v.y,h1,m1_,l1);
    bf16_split3(v.z,h2,m2_,l2); bf16_split3(v.w,h3,m3_,l3);
    *(ushort4*)&AsH[r*264+kq] = make_ushort4(h0,h1,h2,h3);
    *(ushort4*)&AsM[r*264+kq] = make_ushort4(m0_,m1_,m2_,m3_);
    *(ushort4*)&AsL[r*264+kq] = make_ushort4(l0,l1,l2,l3);
  }
  __syncthreads();

  f32x4 acc[16];
  #pragma unroll
  for(int s=0;s<16;s++)
    #pragma unroll
    for(int e=0;e<4;e++) acc[s][e] = 0.f;

  const int rb = wv*16;
  for(int kt=0; kt<8; kt++){
    const int k0 = kt*32;
    const short8_t aH = *(const short8_t*)&AsH[(rb+l15)*264 + k0 + l4*8];
    const short8_t aM = *(const short8_t*)&AsM[(rb+l15)*264 + k0 + l4*8];
    const short8_t aL = *(const short8_t*)&AsL[(rb+l15)*264 + k0 + l4*8];
    #pragma unroll
    for(int fn=0; fn<16; fn++){
      const int n = fn*16 + l15;
      const short8_t bH = *(const short8_t*)(W1H + (size_t)n*256 + k0 + l4*8);
      const short8_t bM = *(const short8_t*)(W1M + (size_t)n*256 + k0 + l4*8);
      const short8_t bL = *(const short8_t*)(W1L + (size_t)n*256 + k0 + l4*8);
      MFMA_X6(aH,aM,aL, bH,bM,bL, acc[fn]);
    }
  }
  #pragma unroll
  for(int fn=0; fn<16; fn++)
    #pragma unroll
    for(int r=0; r<4; r++)
      blend1[(r0 + rb + l4*4 + r)*256 + fn*16 + l15] = acc[fn][r];
}

extern "C" void kernel_launch(void* const* d_in, const int* in_sizes, int n_in,
                              void* d_out, int out_size, void* d_ws, size_t ws_size,
                              hipStream_t stream)
{
  (void)in_sizes; (void)n_in; (void)out_size; (void)ws_size;
  const float* targets  = (const float*)d_in[0];
  const float* h0       = (const float*)d_in[1];
  const float* c0       = (const float*)d_in[2];
  const float* enc_w_ih = (const float*)d_in[3];
  const float* enc_w_hh = (const float*)d_in[4];
  const float* enc_b_ih = (const float*)d_in[5];
  const float* enc_b_hh = (const float*)d_in[6];
  const float* dec_w_ih = (const float*)d_in[7];
  const float* dec_w_hh = (const float*)d_in[8];
  const float* dec_b_ih = (const float*)d_in[9];
  const float* dec_b_hh = (const float*)d_in[10];
  const float* W1       = (const float*)d_in[11];
  const float* W2       = (const float*)d_in[12];
  const float* vt       = (const float*)d_in[13];
  float* outp = (float*)d_out;

  // ---- workspace carve-up (~242 MB) ----
  float* ws      = (float*)d_ws;
  float* blend1  = ws;                               // B*T*256 fp32 (210 MB)
  char* pc = (char*)(blend1 + (size_t)BB*TT*256);
  pc = (char*)(((uintptr_t)pc + 63) & ~(uintptr_t)63);
  unsigned short* q = (unsigned short*)pc;
  const size_t WFSZ = (size_t)1024*KTOT;
  unsigned short* eWfH = q; q += WFSZ*EREP;
  unsigned short* eWfM = q; q += WFSZ*EREP;
  unsigned short* eWfL = q; q += WFSZ*EREP;
  unsigned short* dWfH = q; q += WFSZ*DREP;
  unsigned short* dWfM = q; q += WFSZ*DREP;
  unsigned short* dWfL = q; q += WFSZ*DREP;
  unsigned short* w2fH = q; q += (size_t)256*256*DREP;
  unsigned short* w2fM = q; q += (size_t)256*256*DREP;
  unsigned short* w2fL = q; q += (size_t)256*256*DREP;
  unsigned short* w1H  = q; q += (size_t)256*256;
  unsigned short* w1M  = q; q += (size_t)256*256;
  unsigned short* w1L  = q; q += (size_t)256*256;

  // ---- prep ----
  const int packGrid = (1024*KTOT + 255)/256;
  k_packW<<<packGrid, 256, 0, stream>>>(enc_w_ih, enc_w_hh, eWfH, eWfM, eWfL, EREP);
  k_packW<<<packGrid, 256, 0, stream>>>(dec_w_ih, dec_w_hh, dWfH, dWfM, dWfL, DREP);
  k_packW2<<<(256*256+255)/256, 256, 0, stream>>>(W2, w2fH, w2fM, w2fL);
  k_split3<<<(256*256+255)/256, 256, 0, stream>>>(W1, w1H, w1M, w1L, 256*256);

  // ---- encoder: 128 blocks x 16 rows, 100 steps in-block ----
  k_encoder<<<BB/EROWS, ENTHR, 0, stream>>>(targets, eWfH, eWfM, eWfL,
                                            enc_b_ih, enc_b_hh, blend1);

  // ---- blend1 = enc_states @ W1^T, in place ----
  k_blend1<<<BB*TT/32, 128, 0, stream>>>(blend1, w1H, w1M, w1L);

  // ---- decoder: 256 blocks x 8 rows, 100 steps in-block ----
  k_decoder<<<NBLK, NTHR, 0, stream>>>(targets, dWfH, dWfM, dWfL,
                                       w2fH, w2fM, w2fL,
                                       dec_b_ih, dec_b_hh, h0, c0,
                                       vt, blend1, outp);
}